// Round 1
// baseline (1327.889 us; speedup 1.0000x reference)
//
#include <hip/hip_runtime.h>
#include <math.h>

#define BDIM 8
#define FR   257
#define TT   300
#define CC   64
#define NN   (BDIM*TT)      // 2400
#define CPPC 16
#define GG   8
#define CPG  8              // CC/GG
#define KW   3
#define EPSV 1e-5f

#define FT    64            // inner rows per F-tile
#define NTIL  5             // ceil(257/64)
#define ROWS  66            // FT + 2 halo
#define FSTR  65            // LDS row stride: odd -> stride-65 reads conflict-free

#define X1_ELEMS ((size_t)NN*FR*CC)     // 39,475,200
#define HP_ELEMS ((size_t)CPPC*NN*FR)   //  9,868,800

// ---------------- cross-lane helpers: VALU (DPP) instead of LDS-pipe ----------------
// update_dpp(old=0, bound_ctrl=true): invalid source lanes contribute 0 -> safe for sums.
template<int CTRL>
__device__ __forceinline__ float dpp_term(float v) {
    return __int_as_float(
        __builtin_amdgcn_update_dpp(0, __float_as_int(v), CTRL, 0xf, 0xf, true));
}
template<int PAT>
__device__ __forceinline__ float swz_term(float v) {
    return __int_as_float(__builtin_amdgcn_ds_swizzle(__float_as_int(v), PAT));
}

// Full wave-64 sum, all on the VALU pipe:
// row_shr 1/2/4/8 -> lane15/31/47/63 hold 16-row sums;
// row_bcast15 -> lane31=sum(0..31), lane63=sum(32..63);
// row_bcast31 -> lane63=total; readlane(63) broadcasts via SGPR.
__device__ __forceinline__ float wave_sum64(float v) {
    v += dpp_term<0x111>(v);   // row_shr:1
    v += dpp_term<0x112>(v);   // row_shr:2
    v += dpp_term<0x114>(v);   // row_shr:4
    v += dpp_term<0x118>(v);   // row_shr:8
    v += dpp_term<0x142>(v);   // row_bcast:15
    v += dpp_term<0x143>(v);   // row_bcast:31
    return __int_as_float(__builtin_amdgcn_readlane(__float_as_int(v), 63));
}

__device__ __forceinline__ void ln_stats_dpp(float v, float& m, float& r) {
    float s  = wave_sum64(v);
    float ss = wave_sum64(v*v);
    m = s * (1.0f/64.0f);
    float var = ss * (1.0f/64.0f) - m*m;
    r = rsqrtf(var + EPSV);
}

// Grouped conv (G=8, K=3) via per-lane partials + xor-butterfly gather.
// Lane c holds y[f-1..f+1][c]; Q[d] = contribution of in-channel c to
// out-channel (c&56)|((c&7)^d).  out[c] = sum_d shfl_xor(Q[d], d):
// d=1,2,3 quad_perm DPP; d=7 row_half_mirror DPP; d=4,5,6 ds_swizzle.
__device__ __forceinline__ float conv_row(float y0, float y1, float y2,
                                          const float wq[8][KW]) {
    float q[8];
    #pragma unroll
    for (int d = 0; d < 8; ++d)
        q[d] = y0*wq[d][0] + y1*wq[d][1] + y2*wq[d][2];
    float acc = q[0];
    acc += dpp_term<0xB1>(q[1]);    // quad_perm [1,0,3,2] = xor1
    acc += dpp_term<0x4E>(q[2]);    // quad_perm [2,3,0,1] = xor2
    acc += dpp_term<0x1B>(q[3]);    // quad_perm [3,2,1,0] = xor3
    acc += swz_term<0x101F>(q[4]);  // ds_swizzle xor4
    acc += swz_term<0x141F>(q[5]);  // ds_swizzle xor5
    acc += swz_term<0x181F>(q[6]);  // ds_swizzle xor6
    acc += dpp_term<0x141>(q[7]);   // row_half_mirror = xor7
    return acc;
}

// ---------------- Kernel 1: LN1 + freq_conv1 + PReLU + res + LN2 + reduce + silu ----------------
__global__ __launch_bounds__(256, 4)
void k_fc1(const float* __restrict__ h,
           const float* __restrict__ g1, const float* __restrict__ b1,
           const float* __restrict__ w1, const float* __restrict__ cb1,
           const float* __restrict__ a1,
           const float* __restrict__ g2, const float* __restrict__ b2,
           const float* __restrict__ redw, const float* __restrict__ redb,
           float* __restrict__ x1, float* __restrict__ hpT)
{
    __shared__ float ys[ROWS*FSTR];   // normalized row state (only LDS buffer)

    const int n  = blockIdx.x;
    const int f0 = blockIdx.y * FT;
    const int nf = min(FT, FR - f0);
    const int b = n / TT, t = n - b*TT;
    const int tid = threadIdx.x;
    const int lane = tid & 63, wid = tid >> 6;

    // weights for butterfly-conv: wq[d][k] = w[cout=(lane&56)|((lane&7)^d)][cin=lane&7][k]
    const int l8 = lane & 7;
    const int gbase = lane & 56;
    float wq[8][KW];
    #pragma unroll
    for (int d = 0; d < 8; ++d) {
        const float* wp = w1 + (size_t)(gbase | (l8 ^ d))*(CPG*KW) + l8*KW;
        #pragma unroll
        for (int k = 0; k < KW; ++k) wq[d][k] = wp[k];
    }
    const float alpha = a1[0];
    const float gA = g1[lane], bA = b1[lane];
    const float gB = g2[lane], bB = b2[lane];
    const float cbv = cb1[lane];

    float xreg[17];   // residual state stays in registers (same row<->wave ownership in all phases)

    // Phase A: load h rows (with halo), LN1 via DPP -> ys; raw value -> xreg
    const size_t hb0 = ((size_t)b*FR*TT + t)*CC;
    #pragma unroll
    for (int it = 0; it < 17; ++it) {
        int lr = wid + it*4;
        if (lr >= ROWS) continue;
        int f = f0 - 1 + lr;
        if (f >= 0 && f < FR) {
            float v = h[hb0 + (size_t)f*TT*CC + lane];
            xreg[it] = v;
            float m, r; ln_stats_dpp(v, m, r);
            ys[lr*FSTR + lane] = (v - m) * r * gA + bA;
        } else {
            xreg[it] = 0.0f;
            ys[lr*FSTR + lane] = 0.0f;
        }
    }
    __syncthreads();

    // Phase B: conv (2 LDS reads + butterfly) + PReLU + residual; x2 -> xreg, x1 -> global
    #pragma unroll
    for (int it = 0; it < 17; ++it) {
        int lr = wid + it*4;
        if (lr < 1 || lr > nf) continue;
        float y0 = ys[(lr-1)*FSTR + lane];   // zero rows handle f-1<0 / f+1>=FR taps
        float y1 = ys[ lr   *FSTR + lane];
        float y2 = ys[(lr+1)*FSTR + lane];
        float acc = conv_row(y0, y1, y2, wq) + cbv;
        float pr = acc >= 0.0f ? acc : alpha*acc;
        float xv = xreg[it] + pr;
        xreg[it] = xv;
        int f = f0 + lr - 1;
        x1[(size_t)n*FR*CC + (size_t)f*CC + lane] = xv;
    }
    __syncthreads();   // all conv reads of LN1-ys complete before LN2 overwrites

    // Phase C: LN2 (DPP) on register state -> ys
    #pragma unroll
    for (int it = 0; it < 17; ++it) {
        int lr = wid + it*4;
        if (lr < 1 || lr > nf) continue;
        float v = xreg[it];
        float m, r; ln_stats_dpp(v, m, r);
        ys[lr*FSTR + lane] = (v - m) * r * gB + bB;
    }
    __syncthreads();

    // Phase D: reduce to CPP=16 + silu. lane = inner row, wave owns 4 p's.
    // Weights wave-uniform -> scalar loads; LDS reads stride-65 conflict-free.
    {
        const int L = lane;
        const int lr = (L < nf) ? (L + 1) : 1;
        const int p0 = wid * 4;
        const float* wp0 = redw + (size_t)(p0+0)*CC;
        const float* wp1 = redw + (size_t)(p0+1)*CC;
        const float* wp2 = redw + (size_t)(p0+2)*CC;
        const float* wp3 = redw + (size_t)(p0+3)*CC;
        float a0 = redb[p0+0], a1v = redb[p0+1], a2 = redb[p0+2], a3 = redb[p0+3];
        #pragma unroll 16
        for (int c = 0; c < CC; ++c) {
            float yv = ys[lr*FSTR + c];
            a0  += yv * wp0[c];
            a1v += yv * wp1[c];
            a2  += yv * wp2[c];
            a3  += yv * wp3[c];
        }
        if (L < nf) {
            int f = f0 + L;
            float s0 = a0  / (1.0f + expf(-a0));
            float s1 = a1v / (1.0f + expf(-a1v));
            float s2 = a2  / (1.0f + expf(-a2));
            float s3 = a3  / (1.0f + expf(-a3));
            size_t base = (size_t)n*FR + f;
            hpT[(size_t)(p0+0)*(NN*FR) + base] = s0;
            hpT[(size_t)(p0+1)*(NN*FR) + base] = s1;
            hpT[(size_t)(p0+2)*(NN*FR) + base] = s2;
            hpT[(size_t)(p0+3)*(NN*FR) + base] = s3;
        }
    }
}

// ---------------- Kernel 2: 16 batched GEMMs  out[n,f'] = sum_f A[n,f]*B[f',f] ----------------
// (unchanged this round for clean attribution; next-round target)
#define BM 64
#define BN 64
#define BK 32
#define LDT 72

__global__ __launch_bounds__(256, 2)
void k_fgemm(const float* __restrict__ hpT, const float* __restrict__ fW,
             const float* __restrict__ fB, float* __restrict__ hp2T)
{
    __shared__ __align__(16) float As[BK*LDT];
    __shared__ __align__(16) float Bs[BK*LDT];
    const int c  = blockIdx.z;
    const int m0 = blockIdx.x * BM;
    const int f0 = blockIdx.y * BN;
    const int tid = threadIdx.x;
    const int tm = tid & 15, tn = tid >> 4;

    const float* Ab = hpT + (size_t)c*(NN*FR);
    const float* Bb = fW  + (size_t)c*(FR*FR);

    float acc[4][4];
    #pragma unroll
    for (int i = 0; i < 4; ++i)
        #pragma unroll
        for (int j = 0; j < 4; ++j) acc[i][j] = 0.0f;

    for (int k0 = 0; k0 < FR; k0 += BK) {
        #pragma unroll
        for (int l = 0; l < 8; ++l) {
            int e = tid + l*256;
            int r = e >> 5, kc = e & 31;
            int m = m0 + r, k = k0 + kc;
            As[kc*LDT + r] = (m < NN && k < FR) ? Ab[(size_t)m*FR + k] : 0.0f;
            int fr = f0 + r;
            Bs[kc*LDT + r] = (fr < FR && k < FR) ? Bb[(size_t)fr*FR + k] : 0.0f;
        }
        __syncthreads();
        #pragma unroll
        for (int k = 0; k < BK; ++k) {
            const float4 av = *reinterpret_cast<const float4*>(&As[k*LDT + (tm<<2)]);
            const float4 bv = *reinterpret_cast<const float4*>(&Bs[k*LDT + (tn<<2)]);
            acc[0][0] += av.x*bv.x; acc[0][1] += av.x*bv.y; acc[0][2] += av.x*bv.z; acc[0][3] += av.x*bv.w;
            acc[1][0] += av.y*bv.x; acc[1][1] += av.y*bv.y; acc[1][2] += av.y*bv.z; acc[1][3] += av.y*bv.w;
            acc[2][0] += av.z*bv.x; acc[2][1] += av.z*bv.y; acc[2][2] += av.z*bv.z; acc[2][3] += av.z*bv.w;
            acc[3][0] += av.w*bv.x; acc[3][1] += av.w*bv.y; acc[3][2] += av.w*bv.z; acc[3][3] += av.w*bv.w;
        }
        __syncthreads();
    }

    #pragma unroll
    for (int i = 0; i < 4; ++i) {
        int m = m0 + (tm<<2) + i;
        if (m >= NN) continue;
        #pragma unroll
        for (int j = 0; j < 4; ++j) {
            int fr = f0 + (tn<<2) + j;
            if (fr < FR)
                hp2T[(size_t)c*(NN*FR) + (size_t)m*FR + fr] = acc[i][j] + fB[c*FR + fr];
        }
    }
}

// ---------------- Kernel 3: expand + silu + residual + LN3 + freq_conv2 ----------------
__global__ __launch_bounds__(256, 4)
void k_fc2(const float* __restrict__ x1, const float* __restrict__ hp2T,
           const float* __restrict__ expw, const float* __restrict__ expb,
           const float* __restrict__ g3, const float* __restrict__ b3,
           const float* __restrict__ w2, const float* __restrict__ cb2,
           const float* __restrict__ a2,
           float* __restrict__ out)
{
    __shared__ float ys[ROWS*FSTR];

    const int n  = blockIdx.x;
    const int f0 = blockIdx.y * FT;
    const int nf = min(FT, FR - f0);
    const int b = n / TT, t = n - b*TT;
    const int tid = threadIdx.x;
    const int lane = tid & 63, wid = tid >> 6;

    const int l8 = lane & 7;
    const int gbase = lane & 56;
    float wq[8][KW];
    #pragma unroll
    for (int d = 0; d < 8; ++d) {
        const float* wp = w2 + (size_t)(gbase | (l8 ^ d))*(CPG*KW) + l8*KW;
        #pragma unroll
        for (int k = 0; k < KW; ++k) wq[d][k] = wp[k];
    }
    float ew[CPPC];
    #pragma unroll
    for (int p = 0; p < CPPC; ++p) ew[p] = expw[lane*CPPC + p];
    const float ebv = expb[lane];
    const float gC = g3[lane], bC = b3[lane];
    const float alpha = a2[0];
    const float cbv = cb2[lane];

    float xreg[17];

    // Phase A: x2 = x1 + silu(expand(hp2)) for all rows (halo incl); LN3 (DPP) -> ys
    // hp2T values wave-uniform per row -> scalar loads, no LDS staging.
    #pragma unroll
    for (int it = 0; it < 17; ++it) {
        int lr = wid + it*4;
        if (lr >= ROWS) continue;
        int f = f0 - 1 + lr;
        if (f >= 0 && f < FR) {
            size_t base = (size_t)n*FR + f;
            float z = ebv;
            #pragma unroll
            for (int p = 0; p < CPPC; ++p)
                z += hp2T[(size_t)p*(NN*FR) + base] * ew[p];
            float sg = z / (1.0f + expf(-z));
            float v = x1[(size_t)n*FR*CC + (size_t)f*CC + lane] + sg;
            xreg[it] = v;
            float m, r; ln_stats_dpp(v, m, r);
            ys[lr*FSTR + lane] = (v - m) * r * gC + bC;
        } else {
            xreg[it] = 0.0f;
            ys[lr*FSTR + lane] = 0.0f;
        }
    }
    __syncthreads();

    // Phase B: conv2 + PReLU + residual -> out in [B, FR, TT, CC]
    const size_t ob0 = ((size_t)b*FR*TT + t)*CC;
    #pragma unroll
    for (int it = 0; it < 17; ++it) {
        int lr = wid + it*4;
        if (lr < 1 || lr > nf) continue;
        float y0 = ys[(lr-1)*FSTR + lane];
        float y1 = ys[ lr   *FSTR + lane];
        float y2 = ys[(lr+1)*FSTR + lane];
        float acc = conv_row(y0, y1, y2, wq) + cbv;
        float pr = acc >= 0.0f ? acc : alpha*acc;
        int f = f0 + lr - 1;
        out[ob0 + (size_t)f*TT*CC + lane] = xreg[it] + pr;
    }
}

extern "C" void kernel_launch(void* const* d_in, const int* in_sizes, int n_in,
                              void* d_out, int out_size, void* d_ws, size_t ws_size,
                              hipStream_t stream) {
    const float* h      = (const float*)d_in[0];
    const float* fc1_g  = (const float*)d_in[1];
    const float* fc1_b  = (const float*)d_in[2];
    const float* fc1_w  = (const float*)d_in[3];
    const float* fc1_cb = (const float*)d_in[4];
    const float* fc1_a  = (const float*)d_in[5];
    const float* fbl_g  = (const float*)d_in[6];
    const float* fbl_b  = (const float*)d_in[7];
    const float* red_w  = (const float*)d_in[8];
    const float* red_b  = (const float*)d_in[9];
    const float* fW     = (const float*)d_in[10];
    const float* fB     = (const float*)d_in[11];
    const float* exp_w  = (const float*)d_in[12];
    const float* exp_b  = (const float*)d_in[13];
    const float* fc2_g  = (const float*)d_in[14];
    const float* fc2_b  = (const float*)d_in[15];
    const float* fc2_w  = (const float*)d_in[16];
    const float* fc2_cb = (const float*)d_in[17];
    const float* fc2_a  = (const float*)d_in[18];

    float* ws   = (float*)d_ws;
    float* x1   = ws;
    float* hpT  = x1 + X1_ELEMS;
    float* hp2T = hpT + HP_ELEMS;

    dim3 g1(NN, NTIL);
    k_fc1<<<g1, 256, 0, stream>>>(h, fc1_g, fc1_b, fc1_w, fc1_cb, fc1_a,
                                  fbl_g, fbl_b, red_w, red_b, x1, hpT);

    dim3 g2((NN + BM - 1)/BM, (FR + BN - 1)/BN, CPPC);
    k_fgemm<<<g2, 256, 0, stream>>>(hpT, fW, fB, hp2T);

    dim3 g3(NN, NTIL);
    k_fc2<<<g3, 256, 0, stream>>>(x1, hp2T, exp_w, exp_b,
                                  fc2_g, fc2_b, fc2_w, fc2_cb, fc2_a,
                                  (float*)d_out);
}

// Round 2
// 943.395 us; speedup vs baseline: 1.4076x; 1.4076x over previous
//
#include <hip/hip_runtime.h>
#include <math.h>

#define BDIM 8
#define FR   257
#define TT   300
#define CC   64
#define NN   (BDIM*TT)      // 2400
#define CPPC 16
#define GG   8
#define CPG  8              // CC/GG
#define KW   3
#define EPSV 1e-5f

#define FT    64            // inner rows per F-tile
#define NTIL  5             // ceil(257/64)
#define ROWS  66            // FT + 2 halo
#define FSTR  65            // LDS row stride: odd -> stride-65 reads conflict-free

#define X1_ELEMS ((size_t)NN*FR*CC)     // 39,475,200
#define HP_ELEMS ((size_t)CPPC*NN*FR)   //  9,868,800

// ---------------- cross-lane helpers: VALU (DPP) instead of LDS-pipe ----------------
// update_dpp(old=0, bound_ctrl=true): invalid source lanes contribute 0 -> safe for sums.
template<int CTRL>
__device__ __forceinline__ float dpp_term(float v) {
    return __int_as_float(
        __builtin_amdgcn_update_dpp(0, __float_as_int(v), CTRL, 0xf, 0xf, true));
}
template<int PAT>
__device__ __forceinline__ float swz_term(float v) {
    return __int_as_float(__builtin_amdgcn_ds_swizzle(__float_as_int(v), PAT));
}

// Full wave-64 sum, all on the VALU pipe:
// row_shr 1/2/4/8 -> lane15/31/47/63 hold 16-row sums;
// row_bcast15 -> lane31=sum(0..31), lane63=sum(32..63);
// row_bcast31 -> lane63=total; readlane(63) broadcasts via SGPR.
__device__ __forceinline__ float wave_sum64(float v) {
    v += dpp_term<0x111>(v);   // row_shr:1
    v += dpp_term<0x112>(v);   // row_shr:2
    v += dpp_term<0x114>(v);   // row_shr:4
    v += dpp_term<0x118>(v);   // row_shr:8
    v += dpp_term<0x142>(v);   // row_bcast:15
    v += dpp_term<0x143>(v);   // row_bcast:31
    return __int_as_float(__builtin_amdgcn_readlane(__float_as_int(v), 63));
}

__device__ __forceinline__ void ln_stats_dpp(float v, float& m, float& r) {
    float s  = wave_sum64(v);
    float ss = wave_sum64(v*v);
    m = s * (1.0f/64.0f);
    float var = ss * (1.0f/64.0f) - m*m;
    r = rsqrtf(var + EPSV);
}

// Grouped conv (G=8, K=3) via per-lane partials + xor-butterfly gather.
// Lane c holds y[f-1..f+1][c]; Q[d] = contribution of in-channel c to
// out-channel (c&56)|((c&7)^d).  out[c] = sum_d shfl_xor(Q[d], d):
// d=1,2,3 quad_perm DPP; d=7 row_half_mirror DPP; d=4,5,6 ds_swizzle.
__device__ __forceinline__ float conv_row(float y0, float y1, float y2,
                                          const float wq[8][KW]) {
    float q[8];
    #pragma unroll
    for (int d = 0; d < 8; ++d)
        q[d] = y0*wq[d][0] + y1*wq[d][1] + y2*wq[d][2];
    float acc = q[0];
    acc += dpp_term<0xB1>(q[1]);    // quad_perm [1,0,3,2] = xor1
    acc += dpp_term<0x4E>(q[2]);    // quad_perm [2,3,0,1] = xor2
    acc += dpp_term<0x1B>(q[3]);    // quad_perm [3,2,1,0] = xor3
    acc += swz_term<0x101F>(q[4]);  // ds_swizzle xor4
    acc += swz_term<0x141F>(q[5]);  // ds_swizzle xor5
    acc += swz_term<0x181F>(q[6]);  // ds_swizzle xor6
    acc += dpp_term<0x141>(q[7]);   // row_half_mirror = xor7
    return acc;
}

// ---------------- Kernel 1: LN1 + freq_conv1 + PReLU + res + LN2 + reduce + silu ----------------
__global__ __launch_bounds__(256, 4)
void k_fc1(const float* __restrict__ h,
           const float* __restrict__ g1, const float* __restrict__ b1,
           const float* __restrict__ w1, const float* __restrict__ cb1,
           const float* __restrict__ a1,
           const float* __restrict__ g2, const float* __restrict__ b2,
           const float* __restrict__ redw, const float* __restrict__ redb,
           float* __restrict__ x1, float* __restrict__ hpT)
{
    __shared__ float xs[ROWS*FSTR];   // residual row state (avoids 17-reg array -> no spills)
    __shared__ float ys[ROWS*FSTR];   // normalized row state

    const int n  = blockIdx.x;
    const int f0 = blockIdx.y * FT;
    const int nf = min(FT, FR - f0);
    const int b = n / TT, t = n - b*TT;
    const int tid = threadIdx.x;
    const int lane = tid & 63, wid = tid >> 6;

    const float alpha = a1[0];
    const float gA = g1[lane], bA = b1[lane];
    const float gB = g2[lane], bB = b2[lane];
    const float cbv = cb1[lane];

    // Phase A: load h rows (with halo), LN1 via DPP -> ys; raw value -> xs
    const size_t hb0 = ((size_t)b*FR*TT + t)*CC;
    #pragma unroll
    for (int it = 0; it < 17; ++it) {
        int lr = wid + it*4;
        if (lr >= ROWS) continue;
        int f = f0 - 1 + lr;
        if (f >= 0 && f < FR) {
            float v = h[hb0 + (size_t)f*TT*CC + lane];
            xs[lr*FSTR + lane] = v;
            float m, r; ln_stats_dpp(v, m, r);
            ys[lr*FSTR + lane] = (v - m) * r * gA + bA;
        } else {
            xs[lr*FSTR + lane] = 0.0f;
            ys[lr*FSTR + lane] = 0.0f;
        }
    }
    __syncthreads();

    // conv weights loaded AFTER Phase A so wq's live range doesn't overlap LN work.
    // wq[d][k] = w[cout=(lane&56)|((lane&7)^d)][cin=lane&7][k]
    const int l8 = lane & 7;
    const int gbase = lane & 56;
    float wq[8][KW];
    #pragma unroll
    for (int d = 0; d < 8; ++d) {
        const float* wp = w1 + (size_t)(gbase | (l8 ^ d))*(CPG*KW) + l8*KW;
        #pragma unroll
        for (int k = 0; k < KW; ++k) wq[d][k] = wp[k];
    }

    // Phase B: conv (3 LDS reads + butterfly) + PReLU + residual; x2 -> xs, x1 -> global
    #pragma unroll
    for (int it = 0; it < 17; ++it) {
        int lr = wid + it*4;
        if (lr < 1 || lr > nf) continue;
        float y0 = ys[(lr-1)*FSTR + lane];   // zero rows handle f-1<0 / f+1>=FR taps
        float y1 = ys[ lr   *FSTR + lane];
        float y2 = ys[(lr+1)*FSTR + lane];
        float acc = conv_row(y0, y1, y2, wq) + cbv;
        float pr = acc >= 0.0f ? acc : alpha*acc;
        float xv = xs[lr*FSTR + lane] + pr;   // same thread wrote this slot in Phase A
        xs[lr*FSTR + lane] = xv;
        int f = f0 + lr - 1;
        x1[(size_t)n*FR*CC + (size_t)f*CC + lane] = xv;
    }
    __syncthreads();   // all conv reads of LN1-ys complete before LN2 overwrites

    // Phase C: LN2 (DPP) -> ys
    #pragma unroll
    for (int it = 0; it < 17; ++it) {
        int lr = wid + it*4;
        if (lr < 1 || lr > nf) continue;
        float v = xs[lr*FSTR + lane];         // same-thread slot
        float m, r; ln_stats_dpp(v, m, r);
        ys[lr*FSTR + lane] = (v - m) * r * gB + bB;
    }
    __syncthreads();

    // Phase D: reduce to CPP=16 + silu. lane = inner row, wave owns 4 p's.
    // Weights wave-uniform -> scalar loads; LDS reads stride-65 conflict-free.
    {
        const int L = lane;
        const int lr = (L < nf) ? (L + 1) : 1;
        const int p0 = wid * 4;
        const float* wp0 = redw + (size_t)(p0+0)*CC;
        const float* wp1 = redw + (size_t)(p0+1)*CC;
        const float* wp2 = redw + (size_t)(p0+2)*CC;
        const float* wp3 = redw + (size_t)(p0+3)*CC;
        float a0 = redb[p0+0], a1v = redb[p0+1], a2 = redb[p0+2], a3 = redb[p0+3];
        #pragma unroll 16
        for (int c = 0; c < CC; ++c) {
            float yv = ys[lr*FSTR + c];
            a0  += yv * wp0[c];
            a1v += yv * wp1[c];
            a2  += yv * wp2[c];
            a3  += yv * wp3[c];
        }
        if (L < nf) {
            int f = f0 + L;
            float s0 = a0  / (1.0f + expf(-a0));
            float s1 = a1v / (1.0f + expf(-a1v));
            float s2 = a2  / (1.0f + expf(-a2));
            float s3 = a3  / (1.0f + expf(-a3));
            size_t base = (size_t)n*FR + f;
            hpT[(size_t)(p0+0)*(NN*FR) + base] = s0;
            hpT[(size_t)(p0+1)*(NN*FR) + base] = s1;
            hpT[(size_t)(p0+2)*(NN*FR) + base] = s2;
            hpT[(size_t)(p0+3)*(NN*FR) + base] = s3;
        }
    }
}

// ---------------- Kernel 2: 16 batched GEMMs  out[n,f'] = sum_f A[n,f]*B[f',f] ----------------
// (unchanged this round for clean attribution; next-round target)
#define BM 64
#define BN 64
#define BK 32
#define LDT 72

__global__ __launch_bounds__(256, 2)
void k_fgemm(const float* __restrict__ hpT, const float* __restrict__ fW,
             const float* __restrict__ fB, float* __restrict__ hp2T)
{
    __shared__ __align__(16) float As[BK*LDT];
    __shared__ __align__(16) float Bs[BK*LDT];
    const int c  = blockIdx.z;
    const int m0 = blockIdx.x * BM;
    const int f0 = blockIdx.y * BN;
    const int tid = threadIdx.x;
    const int tm = tid & 15, tn = tid >> 4;

    const float* Ab = hpT + (size_t)c*(NN*FR);
    const float* Bb = fW  + (size_t)c*(FR*FR);

    float acc[4][4];
    #pragma unroll
    for (int i = 0; i < 4; ++i)
        #pragma unroll
        for (int j = 0; j < 4; ++j) acc[i][j] = 0.0f;

    for (int k0 = 0; k0 < FR; k0 += BK) {
        #pragma unroll
        for (int l = 0; l < 8; ++l) {
            int e = tid + l*256;
            int r = e >> 5, kc = e & 31;
            int m = m0 + r, k = k0 + kc;
            As[kc*LDT + r] = (m < NN && k < FR) ? Ab[(size_t)m*FR + k] : 0.0f;
            int fr = f0 + r;
            Bs[kc*LDT + r] = (fr < FR && k < FR) ? Bb[(size_t)fr*FR + k] : 0.0f;
        }
        __syncthreads();
        #pragma unroll
        for (int k = 0; k < BK; ++k) {
            const float4 av = *reinterpret_cast<const float4*>(&As[k*LDT + (tm<<2)]);
            const float4 bv = *reinterpret_cast<const float4*>(&Bs[k*LDT + (tn<<2)]);
            acc[0][0] += av.x*bv.x; acc[0][1] += av.x*bv.y; acc[0][2] += av.x*bv.z; acc[0][3] += av.x*bv.w;
            acc[1][0] += av.y*bv.x; acc[1][1] += av.y*bv.y; acc[1][2] += av.y*bv.z; acc[1][3] += av.y*bv.w;
            acc[2][0] += av.z*bv.x; acc[2][1] += av.z*bv.y; acc[2][2] += av.z*bv.z; acc[2][3] += av.z*bv.w;
            acc[3][0] += av.w*bv.x; acc[3][1] += av.w*bv.y; acc[3][2] += av.w*bv.z; acc[3][3] += av.w*bv.w;
        }
        __syncthreads();
    }

    #pragma unroll
    for (int i = 0; i < 4; ++i) {
        int m = m0 + (tm<<2) + i;
        if (m >= NN) continue;
        #pragma unroll
        for (int j = 0; j < 4; ++j) {
            int fr = f0 + (tn<<2) + j;
            if (fr < FR)
                hp2T[(size_t)c*(NN*FR) + (size_t)m*FR + fr] = acc[i][j] + fB[c*FR + fr];
        }
    }
}

// ---------------- Kernel 3: expand + silu + residual + LN3 + freq_conv2 ----------------
__global__ __launch_bounds__(256, 4)
void k_fc2(const float* __restrict__ x1, const float* __restrict__ hp2T,
           const float* __restrict__ expw, const float* __restrict__ expb,
           const float* __restrict__ g3, const float* __restrict__ b3,
           const float* __restrict__ w2, const float* __restrict__ cb2,
           const float* __restrict__ a2,
           float* __restrict__ out)
{
    __shared__ float xs[ROWS*FSTR];   // residual row state
    __shared__ float ys[ROWS*FSTR];

    const int n  = blockIdx.x;
    const int f0 = blockIdx.y * FT;
    const int nf = min(FT, FR - f0);
    const int b = n / TT, t = n - b*TT;
    const int tid = threadIdx.x;
    const int lane = tid & 63, wid = tid >> 6;

    const float ebv = expb[lane];
    const float gC = g3[lane], bC = b3[lane];
    const float alpha = a2[0];
    const float cbv = cb2[lane];

    // expand weights: live only during Phase A (wq loaded after)
    float ew[CPPC];
    #pragma unroll
    for (int p = 0; p < CPPC; ++p) ew[p] = expw[lane*CPPC + p];

    // Phase A: x2 = x1 + silu(expand(hp2)) for all rows (halo incl); LN3 (DPP) -> ys
    // hp2T values wave-uniform per row -> scalar loads, no LDS staging.
    #pragma unroll
    for (int it = 0; it < 17; ++it) {
        int lr = wid + it*4;
        if (lr >= ROWS) continue;
        int f = f0 - 1 + lr;
        if (f >= 0 && f < FR) {
            size_t base = (size_t)n*FR + f;
            float z = ebv;
            #pragma unroll
            for (int p = 0; p < CPPC; ++p)
                z += hp2T[(size_t)p*(NN*FR) + base] * ew[p];
            float sg = z / (1.0f + expf(-z));
            float v = x1[(size_t)n*FR*CC + (size_t)f*CC + lane] + sg;
            xs[lr*FSTR + lane] = v;
            float m, r; ln_stats_dpp(v, m, r);
            ys[lr*FSTR + lane] = (v - m) * r * gC + bC;
        } else {
            xs[lr*FSTR + lane] = 0.0f;
            ys[lr*FSTR + lane] = 0.0f;
        }
    }
    __syncthreads();

    // conv weights AFTER Phase A: live range doesn't overlap ew
    const int l8 = lane & 7;
    const int gbase = lane & 56;
    float wq[8][KW];
    #pragma unroll
    for (int d = 0; d < 8; ++d) {
        const float* wp = w2 + (size_t)(gbase | (l8 ^ d))*(CPG*KW) + l8*KW;
        #pragma unroll
        for (int k = 0; k < KW; ++k) wq[d][k] = wp[k];
    }

    // Phase B: conv2 + PReLU + residual -> out in [B, FR, TT, CC]
    const size_t ob0 = ((size_t)b*FR*TT + t)*CC;
    #pragma unroll
    for (int it = 0; it < 17; ++it) {
        int lr = wid + it*4;
        if (lr < 1 || lr > nf) continue;
        float y0 = ys[(lr-1)*FSTR + lane];
        float y1 = ys[ lr   *FSTR + lane];
        float y2 = ys[(lr+1)*FSTR + lane];
        float acc = conv_row(y0, y1, y2, wq) + cbv;
        float pr = acc >= 0.0f ? acc : alpha*acc;
        int f = f0 + lr - 1;
        out[ob0 + (size_t)f*TT*CC + lane] = xs[lr*FSTR + lane] + pr;
    }
}

extern "C" void kernel_launch(void* const* d_in, const int* in_sizes, int n_in,
                              void* d_out, int out_size, void* d_ws, size_t ws_size,
                              hipStream_t stream) {
    const float* h      = (const float*)d_in[0];
    const float* fc1_g  = (const float*)d_in[1];
    const float* fc1_b  = (const float*)d_in[2];
    const float* fc1_w  = (const float*)d_in[3];
    const float* fc1_cb = (const float*)d_in[4];
    const float* fc1_a  = (const float*)d_in[5];
    const float* fbl_g  = (const float*)d_in[6];
    const float* fbl_b  = (const float*)d_in[7];
    const float* red_w  = (const float*)d_in[8];
    const float* red_b  = (const float*)d_in[9];
    const float* fW     = (const float*)d_in[10];
    const float* fB     = (const float*)d_in[11];
    const float* exp_w  = (const float*)d_in[12];
    const float* exp_b  = (const float*)d_in[13];
    const float* fc2_g  = (const float*)d_in[14];
    const float* fc2_b  = (const float*)d_in[15];
    const float* fc2_w  = (const float*)d_in[16];
    const float* fc2_cb = (const float*)d_in[17];
    const float* fc2_a  = (const float*)d_in[18];

    float* ws   = (float*)d_ws;
    float* x1   = ws;
    float* hpT  = x1 + X1_ELEMS;
    float* hp2T = hpT + HP_ELEMS;

    dim3 g1(NN, NTIL);
    k_fc1<<<g1, 256, 0, stream>>>(h, fc1_g, fc1_b, fc1_w, fc1_cb, fc1_a,
                                  fbl_g, fbl_b, red_w, red_b, x1, hpT);

    dim3 g2((NN + BM - 1)/BM, (FR + BN - 1)/BN, CPPC);
    k_fgemm<<<g2, 256, 0, stream>>>(hpT, fW, fB, hp2T);

    dim3 g3(NN, NTIL);
    k_fc2<<<g3, 256, 0, stream>>>(x1, hp2T, exp_w, exp_b,
                                  fc2_g, fc2_b, fc2_w, fc2_cb, fc2_a,
                                  (float*)d_out);
}